// Round 9
// baseline (218.995 us; speedup 1.0000x reference)
//
#include <hip/hip_runtime.h>
#include <cmath>

// MLDR loss on MI355X, v8: scan-free streaming + squares recomputed from raw.
//  K1:  raw (4 ch/sig) -> L: per-32-sample local EMA end states, 24 series
//       (6 coefs x 4 streams) x 4 sigs (12.6 MB). No other writes.
//  K2a: within-chunk serial scan over 128 segments -> P (carry at segment
//       start, 12.6 MB) + Y0 (chunk totals).
//  K2b: cross-chunk serial scan -> Y (state at end of each chunk).
//  K3:  streaming long coefs: carry = P + Y*exp2(l2a*sic); recompute squares
//       from raw (L3-hot); emit Etab[24][65536] log-ratios @16-sample grid.
//  K4:  streaming ALL 3 short coefs in one raw pass: 12 states, D=log(yp/yt)
//       per sample, E via register lerp of 4 preloaded table vals; reduce.
//  K5:  fp64 sum / (8*T).
// c-scale cancels in log ratios -> unscaled recurrences; clip 1e-8 (exact).
// P/Y/exp2 streaming-carry math verified absmax=0.0 in R8's v7.

#define T_LEN   1048576
#define G       32
#define SEGS    32768       // per sig
#define CSEGS   128         // segments per chunk (chunk = 4096 samples)
#define CHUNKS  256
#define COLS    65536
#define JMAX    65535
#define EPS     1e-8f

struct K1A  { float d[6]; };
struct K2aA { float aG[6]; };           // d^32
struct K2bA { float dC[6]; };           // d^4096
struct K3A  { float d[3]; float l2a[3]; };   // long coefs (cf = 2k+1)
struct K4A  { float d[3]; float l2a[3]; };   // short coefs (cf = 2k)

// compute one 8-sample tile of the 4 squared streams from raw
__device__ __forceinline__ void sq_tile(
    const float* __restrict__ p0, const float* __restrict__ p1,
    const float* __restrict__ t0, const float* __restrict__ t1, long o,
    float q[4][8])
{
  float4 A0 = *(const float4*)(p0 + o), A1 = *(const float4*)(p0 + o + 4);
  float4 B0 = *(const float4*)(p1 + o), B1 = *(const float4*)(p1 + o + 4);
  float4 C0 = *(const float4*)(t0 + o), C1 = *(const float4*)(t0 + o + 4);
  float4 D0 = *(const float4*)(t1 + o), D1 = *(const float4*)(t1 + o + 4);
  float m;
#define QQ(i, AV, BV, CV, DV, CMP) \
  m = AV.CMP + BV.CMP; q[0][i] = fmaxf(0.5f * m * m, EPS); \
  m = AV.CMP - BV.CMP; q[1][i] = fmaxf(0.5f * m * m, EPS); \
  m = CV.CMP + DV.CMP; q[2][i] = fmaxf(0.5f * m * m, EPS); \
  m = CV.CMP - DV.CMP; q[3][i] = fmaxf(0.5f * m * m, EPS);
  QQ(0,A0,B0,C0,D0,x) QQ(1,A0,B0,C0,D0,y) QQ(2,A0,B0,C0,D0,z) QQ(3,A0,B0,C0,D0,w)
  QQ(4,A1,B1,C1,D1,x) QQ(5,A1,B1,C1,D1,y) QQ(6,A1,B1,C1,D1,z) QQ(7,A1,B1,C1,D1,w)
#undef QQ
}

// ---------------- K1: local EMA states only ----------------
__global__ __launch_bounds__(256)
void k1_stage(const float* __restrict__ xp, const float* __restrict__ xt,
              float* __restrict__ L, K1A ka)
{
  int sig = blockIdx.y;
  int gseg = blockIdx.x * 256 + threadIdx.x;
  long base = (long)gseg * G;
  const float* p0 = xp + (long)sig * 2 * T_LEN;
  const float* p1 = p0 + T_LEN;
  const float* t0 = xt + (long)sig * 2 * T_LEN;
  const float* t1 = t0 + T_LEN;

  float v[24];
#pragma unroll
  for (int j = 0; j < 24; j++) v[j] = 0.f;

#pragma unroll
  for (int tile = 0; tile < 4; tile++) {
    float q[4][8];
    sq_tile(p0, p1, t0, t1, base + tile * 8, q);
#pragma unroll
    for (int i = 0; i < 8; i++) {
#pragma unroll
      for (int cf = 0; cf < 6; cf++) {
        float dd = ka.d[cf];
        v[cf*4+0] = fmaf(dd, v[cf*4+0], q[0][i]);
        v[cf*4+1] = fmaf(dd, v[cf*4+1], q[1][i]);
        v[cf*4+2] = fmaf(dd, v[cf*4+2], q[2][i]);
        v[cf*4+3] = fmaf(dd, v[cf*4+3], q[3][i]);
      }
    }
  }
  float4* Lp = (float4*)(L + ((long)sig * SEGS + gseg) * 24);
#pragma unroll
  for (int cf = 0; cf < 6; cf++) {
    float4 f; f.x = v[cf*4+0]; f.y = v[cf*4+1]; f.z = v[cf*4+2]; f.w = v[cf*4+3];
    Lp[cf] = f;
  }
}

// ---------------- K2a: within-chunk prefix ----------------
__global__ __launch_bounds__(256)
void k2a_scan(const float* __restrict__ L, float* __restrict__ P,
              float* __restrict__ Y0, K2aA ka)
{
  int sig = blockIdx.y;
  int lt = threadIdx.x & 31, grp = threadIdx.x >> 5;
  int chunk = blockIdx.x * 8 + grp;
  if (lt >= 24) return;
  float a = ka.aG[lt >> 2];
  float S = 0.f;
  long rowbase = ((long)sig * SEGS + (long)chunk * CSEGS) * 24 + lt;
#pragma unroll 8
  for (int s = 0; s < CSEGS; s++) {
    long idx = rowbase + (long)s * 24;
    P[idx] = S;                      // state at end of previous segment
    S = fmaf(S, a, L[idx]);
  }
  Y0[((long)sig * CHUNKS + chunk) * 24 + lt] = S;
}

// ---------------- K2b: cross-chunk scan ----------------
__global__ void k2b_scan(const float* __restrict__ Y0, float* __restrict__ Y, K2bA ka)
{
  int t = threadIdx.x;
  if (t >= 96) return;
  int sig = t / 24, j = t % 24;
  float dC = ka.dC[j >> 2];
  float y = 0.f;
#pragma unroll 8
  for (int c = 0; c < CHUNKS; c++) {
    long idx = ((long)sig * CHUNKS + c) * 24 + j;
    y = fmaf(y, dC, Y0[idx]);
    Y[idx] = y;                      // state at END of chunk c
  }
}

// ---------------- K3: streaming long-coef table ----------------
__global__ __launch_bounds__(256)
void k3_table(const float* __restrict__ xp, const float* __restrict__ xt,
              const float* __restrict__ P, const float* __restrict__ Y,
              float* __restrict__ Etab, K3A ka)
{
  int sig = blockIdx.y;
  int gseg = blockIdx.x * 256 + threadIdx.x;
  int chunk = gseg >> 7, sic = gseg & 127;
  long base = (long)gseg * G;
  const float* p0 = xp + (long)sig * 2 * T_LEN;
  const float* p1 = p0 + T_LEN;
  const float* t0 = xt + (long)sig * 2 * T_LEN;
  const float* t1 = t0 + T_LEN;

  float y[12];
  const float* Pb = P + ((long)sig * SEGS + gseg) * 24;
  const float* Yb = Y + ((long)sig * CHUNKS + (chunk - 1)) * 24;
#pragma unroll
  for (int k = 0; k < 3; k++) {
    float4 p4 = *(const float4*)(Pb + (2*k+1)*4);
    float pw = __builtin_amdgcn_exp2f(ka.l2a[k] * (float)sic);
    float4 y4 = {0.f, 0.f, 0.f, 0.f};
    if (chunk > 0) y4 = *(const float4*)(Yb + (2*k+1)*4);
    y[4*k+0] = fmaf(y4.x, pw, p4.x);
    y[4*k+1] = fmaf(y4.y, pw, p4.y);
    y[4*k+2] = fmaf(y4.z, pw, p4.z);
    y[4*k+3] = fmaf(y4.w, pw, p4.w);
  }

  float e15[6], e31[6];
#pragma unroll
  for (int tile = 0; tile < 4; tile++) {
    float q[4][8];
    sq_tile(p0, p1, t0, t1, base + tile * 8, q);
#pragma unroll
    for (int i = 0; i < 8; i++) {
#pragma unroll
      for (int k = 0; k < 3; k++) {
        float dd = ka.d[k];
        y[4*k+0] = fmaf(dd, y[4*k+0], q[0][i]);
        y[4*k+1] = fmaf(dd, y[4*k+1], q[1][i]);
        y[4*k+2] = fmaf(dd, y[4*k+2], q[2][i]);
        y[4*k+3] = fmaf(dd, y[4*k+3], q[3][i]);
      }
    }
    if (tile == 1 || tile == 3) {
      float* dst = (tile == 1) ? e15 : e31;
#pragma unroll
      for (int k = 0; k < 3; k++) {
        dst[2*k+0] = __logf(__fdividef(y[4*k+0], y[4*k+2]));
        dst[2*k+1] = __logf(__fdividef(y[4*k+1], y[4*k+3]));
      }
    }
  }
  long col0 = (long)gseg * 2;
#pragma unroll
  for (int k = 0; k < 3; k++) {
#pragma unroll
    for (int st = 0; st < 2; st++) {
      float2 o; o.x = e15[2*k+st]; o.y = e31[2*k+st];
      *(float2*)(Etab + (long)(k*8 + sig*2 + st) * COLS + col0) = o;
    }
  }
}

// ---------------- K4: streaming, all 3 short coefs, one raw pass ----------------
__global__ __launch_bounds__(256)
void k4_main(const float* __restrict__ xp, const float* __restrict__ xt,
             const float* __restrict__ P, const float* __restrict__ Y,
             const float* __restrict__ Etab, float* __restrict__ part, K4A ka)
{
  int sig = blockIdx.y;
  int gseg = blockIdx.x * 256 + threadIdx.x;
  int chunk = gseg >> 7, sic = gseg & 127;
  long base = (long)gseg * G;
  const float* p0 = xp + (long)sig * 2 * T_LEN;
  const float* p1 = p0 + T_LEN;
  const float* t0 = xt + (long)sig * 2 * T_LEN;
  const float* t1 = t0 + T_LEN;

  float y[12];
  const float* Pb = P + ((long)sig * SEGS + gseg) * 24;
  const float* Yb = Y + ((long)sig * CHUNKS + (chunk - 1)) * 24;
#pragma unroll
  for (int k = 0; k < 3; k++) {
    float4 p4 = *(const float4*)(Pb + (2*k)*4);
    float pw = __builtin_amdgcn_exp2f(ka.l2a[k] * (float)sic);
    float4 y4 = {0.f, 0.f, 0.f, 0.f};
    if (chunk > 0) y4 = *(const float4*)(Yb + (2*k)*4);
    y[4*k+0] = fmaf(y4.x, pw, p4.x);
    y[4*k+1] = fmaf(y4.y, pw, p4.y);
    y[4*k+2] = fmaf(y4.z, pw, p4.z);
    y[4*k+3] = fmaf(y4.w, pw, p4.w);
  }

  // table prefetch per pair (L2/L3-resident Etab, 6 MB)
  float tm[3][4], ts[3][4];
  int qm0a[3], j0a[3], u0a[3]; bool fasta[3];
#pragma unroll
  for (int k = 0; k < 3; k++) {
    const int sh = (k == 0) ? 10804 : ((k == 1) ? 31972 : 63945);
    const float* Tm = Etab + (long)(k*8 + sig*2) * COLS;
    const float* Ts = Tm + COLS;
    int u0 = (int)base + sh; if (u0 >= T_LEN) u0 -= T_LEN;
    int qm0 = u0 - 15, j0 = qm0 >> 4;
    bool fast = (qm0 >= 0) && (u0 + 31 < T_LEN) && (j0 <= JMAX - 3);
    u0a[k] = u0; qm0a[k] = qm0; j0a[k] = j0; fasta[k] = fast;
    int jb = fast ? j0 : 0;
#pragma unroll
    for (int i = 0; i < 4; i++) { tm[k][i] = Tm[jb + i]; ts[k][i] = Ts[jb + i]; }
  }

  float acc = 0.f;
#pragma unroll
  for (int tile = 0; tile < 4; tile++) {
    float q[4][8];
    sq_tile(p0, p1, t0, t1, base + tile * 8, q);
#pragma unroll
    for (int i = 0; i < 8; i++) {
      int idx = tile * 8 + i;
#pragma unroll
      for (int k = 0; k < 3; k++) {
        float dd = ka.d[k];
        y[4*k+0] = fmaf(dd, y[4*k+0], q[0][i]);
        y[4*k+1] = fmaf(dd, y[4*k+1], q[1][i]);
        y[4*k+2] = fmaf(dd, y[4*k+2], q[2][i]);
        y[4*k+3] = fmaf(dd, y[4*k+3], q[3][i]);
        float Dm = __logf(__fdividef(y[4*k+0], y[4*k+2]));
        float Ds = __logf(__fdividef(y[4*k+1], y[4*k+3]));
        float em, es;
        if (fasta[k]) {
          int qi = qm0a[k] + idx;
          int jj = (qi >> 4) - j0a[k];
          float fr = (float)(qi & 15) * 0.0625f;
          float am = (jj == 0) ? tm[k][0] : ((jj == 1) ? tm[k][1] : tm[k][2]);
          float bm = (jj == 0) ? tm[k][1] : ((jj == 1) ? tm[k][2] : tm[k][3]);
          float as = (jj == 0) ? ts[k][0] : ((jj == 1) ? ts[k][1] : ts[k][2]);
          float bs = (jj == 0) ? ts[k][1] : ((jj == 1) ? ts[k][2] : ts[k][3]);
          em = fmaf(fr, bm - am, am);
          es = fmaf(fr, bs - as, as);
        } else {
          const float* Tm2 = Etab + (long)(k*8 + sig*2) * COLS;
          const float* Ts2 = Tm2 + COLS;
          int u = u0a[k] + idx; if (u >= T_LEN) u -= T_LEN;
          int qq = u - 15;
          if (qq < 0) { em = Tm2[0]; es = Ts2[0]; }
          else {
            int j = qq >> 4;
            if (j >= JMAX) { em = Tm2[JMAX]; es = Ts2[JMAX]; }
            else {
              float fr = (float)(qq & 15) * 0.0625f;
              float a = Tm2[j], b = Tm2[j+1];
              em = fmaf(fr, b - a, a);
              a = Ts2[j]; b = Ts2[j+1];
              es = fmaf(fr, b - a, a);
            }
          }
        }
        acc += fabsf(Dm - em) + fabsf(Ds - es);
      }
    }
  }

#pragma unroll
  for (int off = 32; off > 0; off >>= 1) acc += __shfl_down(acc, off, 64);
  __shared__ float psum[4];
  int lane = threadIdx.x & 63, w = threadIdx.x >> 6;
  if (lane == 0) psum[w] = acc;
  __syncthreads();
  if (threadIdx.x == 0)
    part[sig * 128 + blockIdx.x] = psum[0] + psum[1] + psum[2] + psum[3];
}

__global__ void k5_final(const float* __restrict__ part, float* __restrict__ out)
{
  __shared__ double lds[256];
  int tid = threadIdx.x;
  double s = 0.0;
  for (int i = tid; i < 512; i += 256) s += (double)part[i];
  lds[tid] = s; __syncthreads();
  for (int o = 128; o > 0; o >>= 1) {
    if (tid < o) lds[tid] += lds[tid + o];
    __syncthreads();
  }
  if (tid == 0) out[0] = (float)(lds[0] * (1.0 / (8.0 * 1048576.0)));
}

extern "C" void kernel_launch(void* const* d_in, const int* in_sizes, int n_in,
                              void* d_out, int out_size, void* d_ws, size_t ws_size,
                              hipStream_t stream)
{
  (void)in_sizes; (void)n_in; (void)out_size; (void)ws_size;
  const float* xp = (const float*)d_in[0];
  const float* xt = (const float*)d_in[1];
  float* out = (float*)d_out;
  char* ws = (char*)d_ws;

  float* L    = (float*)(ws);                         // 12582912
  float* P    = (float*)(ws + 12582912);              // 12582912
  float* Y0   = (float*)(ws + 25165824);              // 98304
  float* Yb   = (float*)(ws + 25264128);              // 98304
  float* Etab = (float*)(ws + 25362432);              // 6291456
  float* part = (float*)(ws + 31653888);              // 2048

  static const double S_MS[3] = {10.0, 50.0, 100.0};
  static const double L_MS[3] = {500.0, 1500.0, 3000.0};

  K1A k1a; K2aA k2aa; K2bA k2ba; K3A k3a; K4A k4a;
  for (int k = 0; k < 3; k++) {
    for (int which = 0; which < 2; which++) {
      int idx = 2 * k + which;
      double ms = which ? L_MS[k] : S_MS[k];
      float cF = (float)(1.0 - std::exp(-2200.0 / (ms * 44100.0)));
      float dF = 1.0f - cF;               // exact fp32 match to reference
      k1a.d[idx] = dF;
      double a32 = std::pow((double)dF, 32.0);
      k2aa.aG[idx] = (float)a32;
      k2ba.dC[idx] = (float)std::pow((double)dF, 4096.0);
      float l2a = (float)(std::log2(a32));
      if (which) { k3a.d[k] = dF; k3a.l2a[k] = l2a; }
      else       { k4a.d[k] = dF; k4a.l2a[k] = l2a; }
    }
  }

  k1_stage<<<dim3(128, 4), 256, 0, stream>>>(xp, xt, L, k1a);
  k2a_scan<<<dim3(32, 4), 256, 0, stream>>>(L, P, Y0, k2aa);
  k2b_scan<<<1, 128, 0, stream>>>(Y0, Yb, k2ba);
  k3_table<<<dim3(128, 4), 256, 0, stream>>>(xp, xt, P, Yb, Etab, k3a);
  k4_main<<<dim3(128, 4), 256, 0, stream>>>(xp, xt, P, Yb, Etab, part, k4a);
  k5_final<<<1, 256, 0, stream>>>(part, out);
}

// Round 10
// 204.263 us; speedup vs baseline: 1.0721x; 1.0721x over previous
//
#include <hip/hip_runtime.h>
#include <cmath>

// MLDR loss on MI355X, v9: table built from scan state (no raw pass), k4
// split by pair for low VGPR.
//  K1:  raw -> L: per-32-sample local EMA end states (24 series x 4 sigs).
//  K2a: within-chunk serial scan -> P (carry at segment start) + Y0.
//  K2b: cross-chunk serial scan -> Y (state at end of each chunk).
//  K3b: Etab32[24][32768] = long-coef log-ratios at t=32j+31, computed
//       directly from P/Y (NO raw read): state_end(g) = P[g+1]+Y[c-1]*aG^(sic+1)
//       (or Y[c] at chunk end). 3 MB table.
//  K4:  gridDim.z=3 (one short coef per slice, lean regs): streaming carry,
//       recompute squares from raw (L3-hot, shared across slices), D per
//       sample, E via 32-grid lerp of 3 preloaded table values; reduce.
//  K5:  fp64 sum / (8*T).
// c-scale cancels in log ratios; clip 1e-8 exact; carry math verified
// absmax=0.0 (R8). Lerp grid 32: noise averages out over 25M terms.

#define T_LEN   1048576
#define G       32
#define SEGS    32768       // per sig
#define CSEGS   128         // segments per chunk (chunk = 4096 samples)
#define CHUNKS  256
#define COLS32  32768
#define JMAX32  32767
#define EPS     1e-8f

struct K1A  { float d[6]; };
struct K2aA { float aG[6]; };           // d^32
struct K2bA { float dC[6]; };           // d^4096
struct K3bA { float l2aL[3]; };         // log2(d_long^32)
struct K4A  { float d[3]; float l2a[3]; };   // short coefs

// one 8-sample tile of the 4 squared streams from raw
__device__ __forceinline__ void sq_tile(
    const float* __restrict__ p0, const float* __restrict__ p1,
    const float* __restrict__ t0, const float* __restrict__ t1, long o,
    float q[4][8])
{
  float4 A0 = *(const float4*)(p0 + o), A1 = *(const float4*)(p0 + o + 4);
  float4 B0 = *(const float4*)(p1 + o), B1 = *(const float4*)(p1 + o + 4);
  float4 C0 = *(const float4*)(t0 + o), C1 = *(const float4*)(t0 + o + 4);
  float4 D0 = *(const float4*)(t1 + o), D1 = *(const float4*)(t1 + o + 4);
  float m;
#define QQ(i, AV, BV, CV, DV, CMP) \
  m = AV.CMP + BV.CMP; q[0][i] = fmaxf(0.5f * m * m, EPS); \
  m = AV.CMP - BV.CMP; q[1][i] = fmaxf(0.5f * m * m, EPS); \
  m = CV.CMP + DV.CMP; q[2][i] = fmaxf(0.5f * m * m, EPS); \
  m = CV.CMP - DV.CMP; q[3][i] = fmaxf(0.5f * m * m, EPS);
  QQ(0,A0,B0,C0,D0,x) QQ(1,A0,B0,C0,D0,y) QQ(2,A0,B0,C0,D0,z) QQ(3,A0,B0,C0,D0,w)
  QQ(4,A1,B1,C1,D1,x) QQ(5,A1,B1,C1,D1,y) QQ(6,A1,B1,C1,D1,z) QQ(7,A1,B1,C1,D1,w)
#undef QQ
}

// ---------------- K1: local EMA states ----------------
__global__ __launch_bounds__(256)
void k1_stage(const float* __restrict__ xp, const float* __restrict__ xt,
              float* __restrict__ L, K1A ka)
{
  int sig = blockIdx.y;
  int gseg = blockIdx.x * 256 + threadIdx.x;
  long base = (long)gseg * G;
  const float* p0 = xp + (long)sig * 2 * T_LEN;
  const float* p1 = p0 + T_LEN;
  const float* t0 = xt + (long)sig * 2 * T_LEN;
  const float* t1 = t0 + T_LEN;

  float v[24];
#pragma unroll
  for (int j = 0; j < 24; j++) v[j] = 0.f;

#pragma unroll
  for (int tile = 0; tile < 4; tile++) {
    float q[4][8];
    sq_tile(p0, p1, t0, t1, base + tile * 8, q);
#pragma unroll
    for (int i = 0; i < 8; i++) {
#pragma unroll
      for (int cf = 0; cf < 6; cf++) {
        float dd = ka.d[cf];
        v[cf*4+0] = fmaf(dd, v[cf*4+0], q[0][i]);
        v[cf*4+1] = fmaf(dd, v[cf*4+1], q[1][i]);
        v[cf*4+2] = fmaf(dd, v[cf*4+2], q[2][i]);
        v[cf*4+3] = fmaf(dd, v[cf*4+3], q[3][i]);
      }
    }
  }
  float4* Lp = (float4*)(L + ((long)sig * SEGS + gseg) * 24);
#pragma unroll
  for (int cf = 0; cf < 6; cf++) {
    float4 f; f.x = v[cf*4+0]; f.y = v[cf*4+1]; f.z = v[cf*4+2]; f.w = v[cf*4+3];
    Lp[cf] = f;
  }
}

// ---------------- K2a: within-chunk prefix ----------------
__global__ __launch_bounds__(256)
void k2a_scan(const float* __restrict__ L, float* __restrict__ P,
              float* __restrict__ Y0, K2aA ka)
{
  int sig = blockIdx.y;
  int lt = threadIdx.x & 31, grp = threadIdx.x >> 5;
  int chunk = blockIdx.x * 8 + grp;
  if (lt >= 24) return;
  float a = ka.aG[lt >> 2];
  float S = 0.f;
  long rowbase = ((long)sig * SEGS + (long)chunk * CSEGS) * 24 + lt;
#pragma unroll 8
  for (int s = 0; s < CSEGS; s++) {
    long idx = rowbase + (long)s * 24;
    P[idx] = S;                      // state at segment start (local)
    S = fmaf(S, a, L[idx]);
  }
  Y0[((long)sig * CHUNKS + chunk) * 24 + lt] = S;
}

// ---------------- K2b: cross-chunk scan ----------------
__global__ void k2b_scan(const float* __restrict__ Y0, float* __restrict__ Y, K2bA ka)
{
  int t = threadIdx.x;
  if (t >= 96) return;
  int sig = t / 24, j = t % 24;
  float dC = ka.dC[j >> 2];
  float y = 0.f;
#pragma unroll 8
  for (int c = 0; c < CHUNKS; c++) {
    long idx = ((long)sig * CHUNKS + c) * 24 + j;
    y = fmaf(y, dC, Y0[idx]);
    Y[idx] = y;                      // global state at END of chunk c
  }
}

// ---------------- K3b: table from scan state (no raw read) ----------------
__global__ __launch_bounds__(256)
void k3b_table(const float* __restrict__ P, const float* __restrict__ Y,
               float* __restrict__ Etab, K3bA ka)
{
  int sig = blockIdx.y;
  int gseg = blockIdx.x * 256 + threadIdx.x;
  int chunk = gseg >> 7, sic = gseg & 127;

  float S[12];                       // long-coef states at end of segment gseg
  if (sic < CSEGS - 1) {
    const float* Pn = P + ((long)sig * SEGS + gseg + 1) * 24;
    const float* Yb = Y + ((long)sig * CHUNKS + (chunk - 1)) * 24;
#pragma unroll
    for (int k = 0; k < 3; k++) {
      float4 p4 = *(const float4*)(Pn + (2*k+1)*4);
      float pw = __builtin_amdgcn_exp2f(ka.l2aL[k] * (float)(sic + 1));
      float4 y4 = {0.f, 0.f, 0.f, 0.f};
      if (chunk > 0) y4 = *(const float4*)(Yb + (2*k+1)*4);
      S[4*k+0] = fmaf(y4.x, pw, p4.x);
      S[4*k+1] = fmaf(y4.y, pw, p4.y);
      S[4*k+2] = fmaf(y4.z, pw, p4.z);
      S[4*k+3] = fmaf(y4.w, pw, p4.w);
    }
  } else {
    const float* Yc = Y + ((long)sig * CHUNKS + chunk) * 24;
#pragma unroll
    for (int k = 0; k < 3; k++) {
      float4 y4 = *(const float4*)(Yc + (2*k+1)*4);
      S[4*k+0] = y4.x; S[4*k+1] = y4.y; S[4*k+2] = y4.z; S[4*k+3] = y4.w;
    }
  }
#pragma unroll
  for (int k = 0; k < 3; k++) {
    float em = __logf(__fdividef(S[4*k+0], S[4*k+2]));
    float es = __logf(__fdividef(S[4*k+1], S[4*k+3]));
    Etab[(long)(k*8 + sig*2 + 0) * COLS32 + gseg] = em;
    Etab[(long)(k*8 + sig*2 + 1) * COLS32 + gseg] = es;
  }
}

// ---------------- K4: one short coef per z-slice ----------------
__global__ __launch_bounds__(256)
void k4_main(const float* __restrict__ xp, const float* __restrict__ xt,
             const float* __restrict__ P, const float* __restrict__ Y,
             const float* __restrict__ Etab, float* __restrict__ part, K4A ka)
{
  int sig = blockIdx.y, pk = blockIdx.z;
  int gseg = blockIdx.x * 256 + threadIdx.x;
  int chunk = gseg >> 7, sic = gseg & 127;
  long base = (long)gseg * G;
  const float* p0 = xp + (long)sig * 2 * T_LEN;
  const float* p1 = p0 + T_LEN;
  const float* t0 = xt + (long)sig * 2 * T_LEN;
  const float* t1 = t0 + T_LEN;
  float d = ka.d[pk];

  // streaming carry
  float4 p4 = *(const float4*)(P + ((long)sig * SEGS + gseg) * 24 + pk * 8);
  float pw = __builtin_amdgcn_exp2f(ka.l2a[pk] * (float)sic);
  float4 yc = {0.f, 0.f, 0.f, 0.f};
  if (chunk > 0)
    yc = *(const float4*)(Y + ((long)sig * CHUNKS + (chunk - 1)) * 24 + pk * 8);
  float y0 = fmaf(yc.x, pw, p4.x), y1 = fmaf(yc.y, pw, p4.y);
  float y2 = fmaf(yc.z, pw, p4.z), y3 = fmaf(yc.w, pw, p4.w);

  // table window: 3 values per stream cover this thread's 32 queries
  const int sh = (pk == 0) ? 10804 : ((pk == 1) ? 31972 : 63945);
  const float* Tm = Etab + (long)(pk*8 + sig*2) * COLS32;
  const float* Ts = Tm + COLS32;
  int u0 = (int)base + sh; if (u0 >= T_LEN) u0 -= T_LEN;
  int qm0 = u0 - 31;
  bool fast = (qm0 >= 0) && (u0 + 31 < T_LEN);
  int j0 = fast ? (qm0 >> 5) : 0;
  if (j0 > JMAX32 - 2) { fast = false; j0 = 0; }
  float tm0 = Tm[j0], tm1 = Tm[j0+1], tm2 = Tm[j0+2];
  float ts0 = Ts[j0], ts1 = Ts[j0+1], ts2 = Ts[j0+2];

  float acc = 0.f;
#pragma unroll
  for (int tile = 0; tile < 4; tile++) {
    float q[4][8];
    sq_tile(p0, p1, t0, t1, base + tile * 8, q);
#pragma unroll
    for (int i = 0; i < 8; i++) {
      int idx = tile * 8 + i;
      y0 = fmaf(d, y0, q[0][i]); y1 = fmaf(d, y1, q[1][i]);
      y2 = fmaf(d, y2, q[2][i]); y3 = fmaf(d, y3, q[3][i]);
      float Dm = __logf(__fdividef(y0, y2));
      float Ds = __logf(__fdividef(y1, y3));
      float em, es;
      if (fast) {
        int qi = qm0 + idx;
        bool hi = (qi >> 5) != j0;
        float fr = (float)(qi & 31) * 0.03125f;
        float am = hi ? tm1 : tm0, bm = hi ? tm2 : tm1;
        float as = hi ? ts1 : ts0, bs = hi ? ts2 : ts1;
        em = fmaf(fr, bm - am, am);
        es = fmaf(fr, bs - as, as);
      } else {
        int u = u0 + idx; if (u >= T_LEN) u -= T_LEN;
        int qq = u - 31;
        if (qq < 0) { em = Tm[0]; es = Ts[0]; }
        else {
          int j = qq >> 5;
          if (j >= JMAX32) { em = Tm[JMAX32]; es = Ts[JMAX32]; }
          else {
            float fr = (float)(qq & 31) * 0.03125f;
            float a = Tm[j], b = Tm[j+1];
            em = fmaf(fr, b - a, a);
            a = Ts[j]; b = Ts[j+1];
            es = fmaf(fr, b - a, a);
          }
        }
      }
      acc += fabsf(Dm - em) + fabsf(Ds - es);
    }
  }

#pragma unroll
  for (int off = 32; off > 0; off >>= 1) acc += __shfl_down(acc, off, 64);
  __shared__ float psum[4];
  int lane = threadIdx.x & 63, w = threadIdx.x >> 6;
  if (lane == 0) psum[w] = acc;
  __syncthreads();
  if (threadIdx.x == 0)
    part[(pk * 4 + sig) * 128 + blockIdx.x] = psum[0] + psum[1] + psum[2] + psum[3];
}

__global__ void k5_final(const float* __restrict__ part, float* __restrict__ out)
{
  __shared__ double lds[256];
  int tid = threadIdx.x;
  double s = 0.0;
  for (int i = tid; i < 1536; i += 256) s += (double)part[i];
  lds[tid] = s; __syncthreads();
  for (int o = 128; o > 0; o >>= 1) {
    if (tid < o) lds[tid] += lds[tid + o];
    __syncthreads();
  }
  if (tid == 0) out[0] = (float)(lds[0] * (1.0 / (8.0 * 1048576.0)));
}

extern "C" void kernel_launch(void* const* d_in, const int* in_sizes, int n_in,
                              void* d_out, int out_size, void* d_ws, size_t ws_size,
                              hipStream_t stream)
{
  (void)in_sizes; (void)n_in; (void)out_size; (void)ws_size;
  const float* xp = (const float*)d_in[0];
  const float* xt = (const float*)d_in[1];
  float* out = (float*)d_out;
  char* ws = (char*)d_ws;

  float* L    = (float*)(ws);                         // 12582912
  float* P    = (float*)(ws + 12582912);              // 12582912
  float* Y0   = (float*)(ws + 25165824);              // 98304
  float* Yb   = (float*)(ws + 25264128);              // 98304
  float* Etab = (float*)(ws + 25362432);              // 24*32768*4 = 3145728
  float* part = (float*)(ws + 28508160);              // 6144

  static const double S_MS[3] = {10.0, 50.0, 100.0};
  static const double L_MS[3] = {500.0, 1500.0, 3000.0};

  K1A k1a; K2aA k2aa; K2bA k2ba; K3bA k3a; K4A k4a;
  for (int k = 0; k < 3; k++) {
    for (int which = 0; which < 2; which++) {
      int idx = 2 * k + which;
      double ms = which ? L_MS[k] : S_MS[k];
      float cF = (float)(1.0 - std::exp(-2200.0 / (ms * 44100.0)));
      float dF = 1.0f - cF;               // exact fp32 match to reference
      k1a.d[idx] = dF;
      double a32 = std::pow((double)dF, 32.0);
      k2aa.aG[idx] = (float)a32;
      k2ba.dC[idx] = (float)std::pow((double)dF, 4096.0);
      float l2a = (float)(std::log2(a32));
      if (which) { k3a.l2aL[k] = l2a; }
      else       { k4a.d[k] = dF; k4a.l2a[k] = l2a; }
    }
  }

  k1_stage<<<dim3(128, 4), 256, 0, stream>>>(xp, xt, L, k1a);
  k2a_scan<<<dim3(32, 4), 256, 0, stream>>>(L, P, Y0, k2aa);
  k2b_scan<<<1, 128, 0, stream>>>(Y0, Yb, k2ba);
  k3b_table<<<dim3(128, 4), 256, 0, stream>>>(P, Yb, Etab, k3a);
  k4_main<<<dim3(128, 4, 3), 256, 0, stream>>>(xp, xt, P, Yb, Etab, part, k4a);
  k5_final<<<1, 256, 0, stream>>>(part, out);
}

// Round 11
// 191.388 us; speedup vs baseline: 1.1442x; 1.0673x over previous
//
#include <hip/hip_runtime.h>
#include <cmath>

// MLDR loss on MI355X, v10: G=16 scan-free streaming, max wave-parallel k4.
//  K1:  raw -> LP: per-16-sample local EMA states, 24 series x 4 sigs (25 MB).
//       One seg per thread (262k threads), 24 coalesced scalar stores.
//  K2a: in-place within-chunk scan (P overwrites L): 96 row-blocks, thread =
//       chunk, float4 steps; emits Y0 chunk totals.
//  K2b: cross-chunk scan over Y0 rows (float4) -> Y.
//  K3b: Etab[24][65536] long log-ratios at 16-grid, from P/Y only (no raw).
//  K4:  grid (256,4,3): one 16-sample seg per thread, carry = P + Y*exp2,
//       squares from raw (L3-hot), D per sample, E via 16-grid lerp of 3
//       preloaded table values; wave reduce -> part. 12k waves, no barriers.
//  K5:  fp64 sum / (8*T).
// c-scale cancels in log ratios; clip 1e-8 exact; carry math & lerp geometry
// both previously validated at absmax 0.0 (R6/R8).

#define T_LEN   1048576
#define G16     16
#define SEGS    65536       // per sig (T/16)
#define CSEGS   256         // segs per chunk (chunk = 4096 samples)
#define CHUNKS  256
#define JMAXT   65535
#define EPS     1e-8f

// plane row: row96 = (cf*4 + st)*4 + sig  (cf in [6), st in [4), sig in [4))
// LP address: row96 * SEGS + seg

struct K1A  { float d[6]; };
struct K2aA { float aG[6]; };            // d^16
struct K2bA { float dC[6]; };            // d^4096
struct K3bA { float l2aL[3]; };          // log2(d_long^16)
struct K4A  { float d[3]; float l2a[3]; };  // short coefs

// ---------------- K1: one seg per thread ----------------
__global__ __launch_bounds__(256)
void k1_stage(const float* __restrict__ xp, const float* __restrict__ xt,
              float* __restrict__ LP, K1A ka)
{
  int sig = blockIdx.y;
  int seg = blockIdx.x * 256 + threadIdx.x;       // [0, 65536)
  long base = (long)seg * G16;
  const float* p0 = xp + (long)sig * 2 * T_LEN;
  const float* p1 = p0 + T_LEN;
  const float* t0 = xt + (long)sig * 2 * T_LEN;
  const float* t1 = t0 + T_LEN;

  float v[24];
#pragma unroll
  for (int j = 0; j < 24; j++) v[j] = 0.f;

#pragma unroll
  for (int tile = 0; tile < 4; tile++) {
    long o = base + tile * 4;
    float4 A = *(const float4*)(p0 + o);
    float4 B = *(const float4*)(p1 + o);
    float4 C = *(const float4*)(t0 + o);
    float4 D = *(const float4*)(t1 + o);
    float q[4][4]; float m;
#define QQ(i, CMP) \
    m = A.CMP + B.CMP; q[0][i] = fmaxf(0.5f * m * m, EPS); \
    m = A.CMP - B.CMP; q[1][i] = fmaxf(0.5f * m * m, EPS); \
    m = C.CMP + D.CMP; q[2][i] = fmaxf(0.5f * m * m, EPS); \
    m = C.CMP - D.CMP; q[3][i] = fmaxf(0.5f * m * m, EPS);
    QQ(0,x) QQ(1,y) QQ(2,z) QQ(3,w)
#undef QQ
#pragma unroll
    for (int i = 0; i < 4; i++) {
#pragma unroll
      for (int cf = 0; cf < 6; cf++) {
        float dd = ka.d[cf];
        v[cf*4+0] = fmaf(dd, v[cf*4+0], q[0][i]);
        v[cf*4+1] = fmaf(dd, v[cf*4+1], q[1][i]);
        v[cf*4+2] = fmaf(dd, v[cf*4+2], q[2][i]);
        v[cf*4+3] = fmaf(dd, v[cf*4+3], q[3][i]);
      }
    }
  }
#pragma unroll
  for (int cf = 0; cf < 6; cf++)
#pragma unroll
    for (int st = 0; st < 4; st++)
      LP[(long)((cf*4 + st)*4 + sig) * SEGS + seg] = v[cf*4+st];
}

// ---------------- K2a: in-place within-chunk scan ----------------
__global__ __launch_bounds__(256)
void k2a_scan(float* __restrict__ LP, float* __restrict__ Y0, K2aA ka)
{
  int row = blockIdx.x;               // [0, 96)
  int chunk = threadIdx.x;            // [0, 256)
  float a = ka.aG[row >> 4];          // cf = row/16
  float S = 0.f;
  float4* b = (float4*)(LP + (long)row * SEGS + (long)chunk * CSEGS);
#pragma unroll 4
  for (int i = 0; i < CSEGS / 4; i++) {
    float4 v = b[i], p;
    p.x = S; S = fmaf(S, a, v.x);
    p.y = S; S = fmaf(S, a, v.y);
    p.z = S; S = fmaf(S, a, v.z);
    p.w = S; S = fmaf(S, a, v.w);
    b[i] = p;                         // P overwrites L (read-before-write)
  }
  Y0[row * CHUNKS + chunk] = S;
}

// ---------------- K2b: cross-chunk scan ----------------
__global__ void k2b_scan(const float* __restrict__ Y0, float* __restrict__ Y, K2bA ka)
{
  int row = threadIdx.x;
  if (row >= 96) return;
  float dC = ka.dC[row >> 4];
  float y = 0.f;
  const float4* s = (const float4*)(Y0 + row * CHUNKS);
  float4* d4 = (float4*)(Y + row * CHUNKS);
#pragma unroll 4
  for (int i = 0; i < CHUNKS / 4; i++) {
    float4 v = s[i], o;
    y = fmaf(y, dC, v.x); o.x = y;
    y = fmaf(y, dC, v.y); o.y = y;
    y = fmaf(y, dC, v.z); o.z = y;
    y = fmaf(y, dC, v.w); o.w = y;
    d4[i] = o;
  }
}

// ---------------- K3b: table from scan state ----------------
__global__ __launch_bounds__(256)
void k3b_table(const float* __restrict__ LP, const float* __restrict__ Y,
               float* __restrict__ Etab, K3bA ka)
{
  int sig = blockIdx.y;
  int gseg = blockIdx.x * 256 + threadIdx.x;
  int c = gseg >> 8, sic = gseg & 255;

#pragma unroll
  for (int k = 0; k < 3; k++) {
    int cf = 2 * k + 1;
    float S[4];
    if (sic < CSEGS - 1) {
      float pw = __builtin_amdgcn_exp2f(ka.l2aL[k] * (float)(sic + 1));
#pragma unroll
      for (int st = 0; st < 4; st++) {
        int row = (cf*4 + st)*4 + sig;
        float P = LP[(long)row * SEGS + gseg + 1];
        float Yp = (c > 0) ? Y[row * CHUNKS + c - 1] : 0.f;
        S[st] = fmaf(Yp, pw, P);
      }
    } else {
#pragma unroll
      for (int st = 0; st < 4; st++) {
        int row = (cf*4 + st)*4 + sig;
        S[st] = Y[row * CHUNKS + c];
      }
    }
    float em = __logf(__fdividef(S[0], S[2]));
    float es = __logf(__fdividef(S[1], S[3]));
    Etab[(long)(k*8 + sig*2 + 0) * SEGS + gseg] = em;
    Etab[(long)(k*8 + sig*2 + 1) * SEGS + gseg] = es;
  }
}

// ---------------- K4: one seg per thread, one pair per z ----------------
__global__ __launch_bounds__(256)
void k4_main(const float* __restrict__ xp, const float* __restrict__ xt,
             const float* __restrict__ LP, const float* __restrict__ Y,
             const float* __restrict__ Etab, float* __restrict__ part, K4A ka)
{
  int sig = blockIdx.y, pk = blockIdx.z;
  int gseg = blockIdx.x * 256 + threadIdx.x;
  int c = gseg >> 8, sic = gseg & 255;
  long base = (long)gseg * G16;
  const float* p0 = xp + (long)sig * 2 * T_LEN;
  const float* p1 = p0 + T_LEN;
  const float* t0 = xt + (long)sig * 2 * T_LEN;
  const float* t1 = t0 + T_LEN;
  float d = ka.d[pk];
  int cf = 2 * pk;

  // streaming carry (4 states)
  float pw = __builtin_amdgcn_exp2f(ka.l2a[pk] * (float)sic);
  float y0, y1, y2, y3;
  {
    int r0 = (cf*4 + 0)*4 + sig, r1 = (cf*4 + 1)*4 + sig;
    int r2 = (cf*4 + 2)*4 + sig, r3 = (cf*4 + 3)*4 + sig;
    float P0 = LP[(long)r0 * SEGS + gseg], P1 = LP[(long)r1 * SEGS + gseg];
    float P2 = LP[(long)r2 * SEGS + gseg], P3 = LP[(long)r3 * SEGS + gseg];
    float Y0v = 0.f, Y1v = 0.f, Y2v = 0.f, Y3v = 0.f;
    if (c > 0) {
      Y0v = Y[r0 * CHUNKS + c - 1]; Y1v = Y[r1 * CHUNKS + c - 1];
      Y2v = Y[r2 * CHUNKS + c - 1]; Y3v = Y[r3 * CHUNKS + c - 1];
    }
    y0 = fmaf(Y0v, pw, P0); y1 = fmaf(Y1v, pw, P1);
    y2 = fmaf(Y2v, pw, P2); y3 = fmaf(Y3v, pw, P3);
  }

  // table window (3 nodes per stream cover the 16 queries)
  const int sh = (pk == 0) ? 10804 : ((pk == 1) ? 31972 : 63945);
  const float* Tm = Etab + (long)(pk*8 + sig*2) * SEGS;
  const float* Ts = Tm + SEGS;
  int u0 = (int)base + sh; if (u0 >= T_LEN) u0 -= T_LEN;
  int qm0 = u0 - 15;
  bool fast = (qm0 >= 0) && (u0 + 15 < T_LEN);
  int j0 = fast ? (qm0 >> 4) : 0;
  if (j0 > JMAXT - 2) { fast = false; j0 = 0; }
  float tm0 = Tm[j0], tm1 = Tm[j0+1], tm2 = Tm[j0+2];
  float ts0 = Ts[j0], ts1 = Ts[j0+1], ts2 = Ts[j0+2];

  float acc = 0.f;
#pragma unroll
  for (int tile = 0; tile < 4; tile++) {
    long o = base + tile * 4;
    float4 A = *(const float4*)(p0 + o);
    float4 B = *(const float4*)(p1 + o);
    float4 C = *(const float4*)(t0 + o);
    float4 D = *(const float4*)(t1 + o);
    float q[4][4]; float m;
#define QQ(i, CMP) \
    m = A.CMP + B.CMP; q[0][i] = fmaxf(0.5f * m * m, EPS); \
    m = A.CMP - B.CMP; q[1][i] = fmaxf(0.5f * m * m, EPS); \
    m = C.CMP + D.CMP; q[2][i] = fmaxf(0.5f * m * m, EPS); \
    m = C.CMP - D.CMP; q[3][i] = fmaxf(0.5f * m * m, EPS);
    QQ(0,x) QQ(1,y) QQ(2,z) QQ(3,w)
#undef QQ
#pragma unroll
    for (int i = 0; i < 4; i++) {
      int idx = tile * 4 + i;
      y0 = fmaf(d, y0, q[0][i]); y1 = fmaf(d, y1, q[1][i]);
      y2 = fmaf(d, y2, q[2][i]); y3 = fmaf(d, y3, q[3][i]);
      float Dm = __logf(__fdividef(y0, y2));
      float Ds = __logf(__fdividef(y1, y3));
      float em, es;
      if (fast) {
        int qi = qm0 + idx;
        bool hi = (qi >> 4) != j0;
        float fr = (float)(qi & 15) * 0.0625f;
        float am = hi ? tm1 : tm0, bm = hi ? tm2 : tm1;
        float as = hi ? ts1 : ts0, bs = hi ? ts2 : ts1;
        em = fmaf(fr, bm - am, am);
        es = fmaf(fr, bs - as, as);
      } else {
        int u = u0 + idx; if (u >= T_LEN) u -= T_LEN;
        int qq = u - 15;
        if (qq < 0) { em = Tm[0]; es = Ts[0]; }
        else {
          int j = qq >> 4;
          if (j >= JMAXT) { em = Tm[JMAXT]; es = Ts[JMAXT]; }
          else {
            float fr = (float)(qq & 15) * 0.0625f;
            float a = Tm[j], b = Tm[j+1];
            em = fmaf(fr, b - a, a);
            a = Ts[j]; b = Ts[j+1];
            es = fmaf(fr, b - a, a);
          }
        }
      }
      acc += fabsf(Dm - em) + fabsf(Ds - es);
    }
  }

#pragma unroll
  for (int off = 32; off > 0; off >>= 1) acc += __shfl_down(acc, off, 64);
  __shared__ float psum[4];
  int lane = threadIdx.x & 63, w = threadIdx.x >> 6;
  if (lane == 0) psum[w] = acc;
  __syncthreads();
  if (threadIdx.x == 0)
    part[(pk * 4 + sig) * 256 + blockIdx.x] = psum[0] + psum[1] + psum[2] + psum[3];
}

__global__ void k5_final(const float* __restrict__ part, float* __restrict__ out)
{
  __shared__ double lds[256];
  int tid = threadIdx.x;
  double s = 0.0;
  for (int i = tid; i < 3072; i += 256) s += (double)part[i];
  lds[tid] = s; __syncthreads();
  for (int o = 128; o > 0; o >>= 1) {
    if (tid < o) lds[tid] += lds[tid + o];
    __syncthreads();
  }
  if (tid == 0) out[0] = (float)(lds[0] * (1.0 / (8.0 * 1048576.0)));
}

extern "C" void kernel_launch(void* const* d_in, const int* in_sizes, int n_in,
                              void* d_out, int out_size, void* d_ws, size_t ws_size,
                              hipStream_t stream)
{
  (void)in_sizes; (void)n_in; (void)out_size; (void)ws_size;
  const float* xp = (const float*)d_in[0];
  const float* xt = (const float*)d_in[1];
  float* out = (float*)d_out;
  char* ws = (char*)d_ws;

  float* LP   = (float*)(ws);                         // 96*65536*4 = 25165824
  float* Y0   = (float*)(ws + 25165824);              // 98304
  float* Yb   = (float*)(ws + 25264128);              // 98304
  float* Etab = (float*)(ws + 25362432);              // 24*65536*4 = 6291456
  float* part = (float*)(ws + 31653888);              // 12288

  static const double S_MS[3] = {10.0, 50.0, 100.0};
  static const double L_MS[3] = {500.0, 1500.0, 3000.0};

  K1A k1a; K2aA k2aa; K2bA k2ba; K3bA k3a; K4A k4a;
  for (int k = 0; k < 3; k++) {
    for (int which = 0; which < 2; which++) {
      int idx = 2 * k + which;
      double ms = which ? L_MS[k] : S_MS[k];
      float cF = (float)(1.0 - std::exp(-2200.0 / (ms * 44100.0)));
      float dF = 1.0f - cF;               // exact fp32 match to reference
      k1a.d[idx] = dF;
      double a16 = std::pow((double)dF, 16.0);
      k2aa.aG[idx] = (float)a16;
      k2ba.dC[idx] = (float)std::pow((double)dF, 4096.0);
      float l2a = (float)(std::log2(a16));
      if (which) { k3a.l2aL[k] = l2a; }
      else       { k4a.d[k] = dF; k4a.l2a[k] = l2a; }
    }
  }

  k1_stage<<<dim3(256, 4), 256, 0, stream>>>(xp, xt, LP, k1a);
  k2a_scan<<<96, 256, 0, stream>>>(LP, Y0, k2aa);
  k2b_scan<<<1, 128, 0, stream>>>(Y0, Yb, k2ba);
  k3b_table<<<dim3(256, 4), 256, 0, stream>>>(LP, Yb, Etab, k3a);
  k4_main<<<dim3(256, 4, 3), 256, 0, stream>>>(xp, xt, LP, Yb, Etab, part, k4a);
  k5_final<<<1, 256, 0, stream>>>(part, out);
}